// Round 12
// baseline (67.857 us; speedup 1.0000x reference)
//
#include <hip/hip_runtime.h>
#include <hip/hip_bf16.h>
#include <hip/hip_fp16.h>
#include <hip/hip_fp8.h>

// Problem constants: B=1,R=2,D=256,NH=8,NP=8,ZA=4,H=W=128,Q=16384,HD=32
#define QN 16384
#define DK 256

typedef float f4_t __attribute__((ext_vector_type(4)));
typedef float f2_t __attribute__((ext_vector_type(2)));
typedef short s16x8 __attribute__((ext_vector_type(8)));
typedef short s16x4 __attribute__((ext_vector_type(4)));
typedef unsigned int u32;
typedef u32 u32x4 __attribute__((ext_vector_type(4)));
typedef u32 u32x2 __attribute__((ext_vector_type(2)));
typedef __fp16 h2_t __attribute__((ext_vector_type(2)));

__device__ inline short f2bf(float f){
  __hip_bfloat16 h = __float2bfloat16(f);
  return __builtin_bit_cast(short, h);
}
__device__ inline u32 pk2h(float a, float b){
#if __has_builtin(__builtin_amdgcn_cvt_pkrtz)
  h2_t r = __builtin_amdgcn_cvt_pkrtz(a, b);
  return __builtin_bit_cast(u32, r);
#else
  return (u32)__builtin_bit_cast(unsigned short, __float2half(a)) |
         ((u32)__builtin_bit_cast(unsigned short, __float2half(b)) << 16);
#endif
}
__device__ inline u32 bperm(u32 s0, u32 s1, u32 sel){
  return __builtin_amdgcn_perm(s0, s1, sel);
}
// fp8 e4m3 pack (2 floats -> low 16 bits) / unpack (HI = immediate template arg)
__device__ inline u32 pk_fp8(float a, float b){
#if __has_builtin(__builtin_amdgcn_cvt_pk_fp8_f32)
  return (u32)__builtin_amdgcn_cvt_pk_fp8_f32(a, b, 0, false);
#else
  __hip_fp8_e4m3 fa(a), fb(b);
  return (u32)fa.__x | ((u32)fb.__x << 8);
#endif
}
template<bool HI>
__device__ inline f2_t upk_fp8(u32 w){
#if __has_builtin(__builtin_amdgcn_cvt_pk_f32_fp8)
  return __builtin_amdgcn_cvt_pk_f32_fp8(w, HI);
#else
  const u32 hh = HI ? (w >> 16) : (w & 0xFFFFu);
  __hip_fp8_e4m3 a, b;
  a.__x = (unsigned char)(hh & 0xFF);
  b.__x = (unsigned char)(hh >> 8);
  return (f2_t){(float)a, (float)b};
#endif
}
// load 8 f32 weights and pack to bf16x8 (replaces the old k_convw round-trip)
__device__ inline s16x8 ldw8(const float* __restrict__ src){
  const f4_t v0 = *(const f4_t*)src;
  const f4_t v1 = *(const f4_t*)(src + 4);
  s16x8 o = { f2bf(v0[0]), f2bf(v0[1]), f2bf(v0[2]), f2bf(v0[3]),
              f2bf(v1[0]), f2bf(v1[1]), f2bf(v1[2]), f2bf(v1[3]) };
  return o;
}

// =============== K1: fused projection GEMM ======================================
// bid < 512:  value-proj tile (BM=64) -> fp8 gather layout vfp8 (LDS-transposed)
// bid >= 512: offset/logit tile (BM=32) -> offw/logit f32
// B-tiles staged straight from the f32 weights (in-register bf16 convert).
__global__ __launch_bounds__(256, 2) void k_proj(const float* __restrict__ value,
    const float* __restrict__ query, const float* __restrict__ Wval,
    const float* __restrict__ Woff, const float* __restrict__ Wattn,
    const float* __restrict__ bval, const float* __restrict__ boff,
    const float* __restrict__ battn, char* __restrict__ vfp8,
    float* __restrict__ offw, float* __restrict__ logit){
  __shared__ short As[64 * 256];
  __shared__ short Bs[64 * 256];
  __shared__ u32 Cs[64 * 16];                 // 4KB fp8 transpose buffer (val path)
  const int tid = threadIdx.x;
  const int lane = tid & 63, wv = tid >> 6;
  const int r16 = lane & 15, kh = lane >> 4;
  const int swsel = (r16 & 7) << 4;
  const int bid = blockIdx.x;

  if (bid < 512){
    // ---------------- value-projection path (BM=64) ----------------
    const float* A = value;
    const int mbase = bid * 64;
    #pragma unroll
    for (int i = 0; i < 16; ++i){
      const int lin = i * 256 + tid;
      const int r = lin >> 6, ck = lin & 63;
      const f4_t v = *(const f4_t*)(A + (size_t)(mbase + r) * DK + ck * 4);
      s16x4 o = { f2bf(v[0]), f2bf(v[1]), f2bf(v[2]), f2bf(v[3]) };
      *(s16x4*)((char*)As + r * 512 + ((ck * 8) ^ ((r & 7) << 4))) = o;
    }
    s16x8 breg[8];
    #pragma unroll
    for (int i = 0; i < 8; ++i){
      const int lin = i * 256 + tid;
      const int n = lin >> 5, ck = lin & 31;
      breg[i] = ldw8(Wval + (size_t)n * DK + ck * 8);
    }
    __syncthreads();
    for (int cg = 0; cg < 4; ++cg){
      #pragma unroll
      for (int i = 0; i < 8; ++i){
        const int lin = i * 256 + tid;
        const int n = lin >> 5, ck = lin & 31;
        *(s16x8*)((char*)Bs + n * 512 + ((ck * 16) ^ ((n & 7) << 4))) = breg[i];
      }
      __syncthreads();
      if (cg < 3){
        #pragma unroll
        for (int i = 0; i < 8; ++i){
          const int lin = i * 256 + tid;
          const int n = lin >> 5, ck = lin & 31;
          breg[i] = ldw8(Wval + (size_t)((cg + 1) * 64 + n) * DK + ck * 8);
        }
      }
      f4_t acc[4];
      #pragma unroll
      for (int i = 0; i < 4; ++i) acc[i] = (f4_t){0.f, 0.f, 0.f, 0.f};
      #pragma unroll
      for (int kk = 0; kk < 8; ++kk){
        const int kb = kh * 16 + kk * 64;
        const s16x8 a = *(const s16x8*)((char*)As + (wv * 16 + r16) * 512 + (kb ^ swsel));
        #pragma unroll
        for (int nt = 0; nt < 4; ++nt){
          const s16x8 b = *(const s16x8*)((char*)Bs + (nt * 16 + r16) * 512 + (kb ^ swsel));
          acc[nt] = __builtin_amdgcn_mfma_f32_16x16x32_bf16(a, b, acc[nt], 0, 0, 0);
        }
      }
      // epilogue: f32 -> fp8, LDS transpose, coalesced 16B stores
      #pragma unroll
      for (int nt = 0; nt < 4; ++nt){
        const int n = cg * 64 + nt * 16 + r16;
        const float bv = bval[n];
        #pragma unroll
        for (int rix = 0; rix < 4; ++rix){
          const float vv = acc[nt][rix] + bv;
          ((char*)Cs)[(wv * 16 + kh * 4 + rix) * 64 + nt * 16 + r16] =
              (char)(pk_fp8(vv, 0.f) & 0xFFu);
        }
      }
      __syncthreads();                          // Cs ready; also fences Bs reads
      {
        const u32x4 cw = *((const u32x4*)((const char*)Cs + tid * 16));
        const int pixl = tid >> 2, q4 = tid & 3;
        const int h2 = cg * 2 + (q4 >> 1);
        const int m = mbase + pixl;
        const int r = m >> 14, pix = m & (QN - 1);
        *(u32x4*)(vfp8 + ((size_t)((r * 8 + h2) * QN + pix)) * 32 + (q4 & 1) * 16) = cw;
      }
    }
  } else {
    // ---------------- offset/logit path (BM=32) ----------------
    const float* A = query;
    const int mg = wv & 1, ch = wv >> 1;
    const int mbase = (bid - 512) * 32;
    #pragma unroll
    for (int i = 0; i < 8; ++i){
      const int lin = i * 256 + tid;
      const int r = lin >> 6, ck = lin & 63;
      const f4_t v = *(const f4_t*)(A + (size_t)(mbase + r) * DK + ck * 4);
      s16x4 o = { f2bf(v[0]), f2bf(v[1]), f2bf(v[2]), f2bf(v[3]) };
      *(s16x4*)((char*)As + r * 512 + ((ck * 8) ^ ((r & 7) << 4))) = o;
    }
    s16x8 breg[8];
    #pragma unroll
    for (int i = 0; i < 8; ++i){
      const int lin = i * 256 + tid;
      const int n = lin >> 5, ck = lin & 31;      // row n (cg=0 -> all W_off)
      breg[i] = ldw8(Woff + (size_t)n * DK + ck * 8);
    }
    __syncthreads();
    for (int cg = 0; cg < 3; ++cg){
      #pragma unroll
      for (int i = 0; i < 8; ++i){
        const int lin = i * 256 + tid;
        const int n = lin >> 5, ck = lin & 31;
        *(s16x8*)((char*)Bs + n * 512 + ((ck * 16) ^ ((n & 7) << 4))) = breg[i];
      }
      __syncthreads();
      if (cg < 2){
        #pragma unroll
        for (int i = 0; i < 8; ++i){
          const int lin = i * 256 + tid;
          const int n = lin >> 5, ck = lin & 31;
          const int rrow = (cg + 1) * 64 + n;     // [64,192)
          const float* src = (rrow < 128) ? (Woff  + (size_t)rrow * DK)
                                          : (Wattn + (size_t)(rrow - 128) * DK);
          breg[i] = ldw8(src + ck * 8);
        }
      }
      f4_t acc[2];
      acc[0] = (f4_t){0.f,0.f,0.f,0.f}; acc[1] = (f4_t){0.f,0.f,0.f,0.f};
      #pragma unroll
      for (int kk = 0; kk < 8; ++kk){
        const int kb = kh * 16 + kk * 64;
        const s16x8 a = *(const s16x8*)((char*)As + (mg * 16 + r16) * 512 + (kb ^ swsel));
        #pragma unroll
        for (int nt = 0; nt < 2; ++nt){
          const s16x8 b = *(const s16x8*)((char*)Bs + (ch * 32 + nt * 16 + r16) * 512 + (kb ^ swsel));
          acc[nt] = __builtin_amdgcn_mfma_f32_16x16x32_bf16(a, b, acc[nt], 0, 0, 0);
        }
      }
      #pragma unroll
      for (int nt = 0; nt < 2; ++nt){
        const int n = cg * 64 + ch * 32 + nt * 16 + r16;
        #pragma unroll
        for (int rix = 0; rix < 4; ++rix){
          const int m = mbase + mg * 16 + kh * 4 + rix;
          const float v = acc[nt][rix];
          if (n < 128) offw[(size_t)m * 128 + n] = v + boff[n];
          else         logit[(size_t)m * 64 + (n - 128)] = v + battn[n - 128];
        }
      }
      __syncthreads();
    }
  }
}

// =============== K4: output projection + bias + residual, BM=32 =================
// A (=O2) bf16 row-major; B staged straight from W_out f32.
__global__ __launch_bounds__(256, 2) void k_gemm_out(const short* __restrict__ Ab,
    const float* __restrict__ Wout, const float* __restrict__ bout,
    const float* __restrict__ query, float* __restrict__ out){
  __shared__ short As[32 * 256];
  __shared__ short Bs[64 * 256];
  const int tid = threadIdx.x;
  const int lane = tid & 63, wv = tid >> 6;
  const int r16 = lane & 15, kh = lane >> 4;
  const int mg = wv & 1, ch = wv >> 1;
  const int swsel = (r16 & 7) << 4;
  const int mbase = blockIdx.x * 32;

  #pragma unroll
  for (int i = 0; i < 4; ++i){
    const int lin = i * 256 + tid;
    const int r = lin >> 5, ck = lin & 31;
    const s16x8 v = *(const s16x8*)(Ab + (size_t)(mbase + r) * DK + ck * 8);
    *(s16x8*)((char*)As + r * 512 + ((ck * 16) ^ ((r & 7) << 4))) = v;
  }
  s16x8 breg[8];
  #pragma unroll
  for (int i = 0; i < 8; ++i){
    const int lin = i * 256 + tid;
    const int n = lin >> 5, ck = lin & 31;
    breg[i] = ldw8(Wout + (size_t)n * DK + ck * 8);
  }
  __syncthreads();

  for (int cg = 0; cg < 4; ++cg){
    #pragma unroll
    for (int i = 0; i < 8; ++i){
      const int lin = i * 256 + tid;
      const int n = lin >> 5, ck = lin & 31;
      *(s16x8*)((char*)Bs + n * 512 + ((ck * 16) ^ ((n & 7) << 4))) = breg[i];
    }
    __syncthreads();
    if (cg < 3){
      #pragma unroll
      for (int i = 0; i < 8; ++i){
        const int lin = i * 256 + tid;
        const int n = lin >> 5, ck = lin & 31;
        breg[i] = ldw8(Wout + (size_t)((cg + 1) * 64 + n) * DK + ck * 8);
      }
    }
    f4_t acc[2];
    acc[0] = (f4_t){0.f,0.f,0.f,0.f}; acc[1] = (f4_t){0.f,0.f,0.f,0.f};
    #pragma unroll
    for (int kk = 0; kk < 8; ++kk){
      const int kb = kh * 16 + kk * 64;
      const s16x8 a = *(const s16x8*)((char*)As + (mg * 16 + r16) * 512 + (kb ^ swsel));
      #pragma unroll
      for (int nt = 0; nt < 2; ++nt){
        const s16x8 b = *(const s16x8*)((char*)Bs + (ch * 32 + nt * 16 + r16) * 512 + (kb ^ swsel));
        acc[nt] = __builtin_amdgcn_mfma_f32_16x16x32_bf16(a, b, acc[nt], 0, 0, 0);
      }
    }
    #pragma unroll
    for (int nt = 0; nt < 2; ++nt){
      const int n = cg * 64 + ch * 32 + nt * 16 + r16;
      const float bo = bout[n];
      #pragma unroll
      for (int rix = 0; rix < 4; ++rix){
        const int m = mbase + mg * 16 + kh * 4 + rix;
        out[(size_t)m * DK + n] = acc[nt][rix] + bo + query[(size_t)m * DK + n];
      }
    }
    __syncthreads();
  }
}

// ---------------- K3: bilinear sampling, fp8 v-cache, 8-lane groups -------------
// EXACT R10 structure (proven correct): shfl broadcasts, 3-deep load pipeline.
__device__ inline void mkw(float rx, float ry, float ox, float oy, float awp,
                           u32& word, u32& pk01, u32& pk23){
  const float x = fmaf(rx, 128.f, ox) - 0.5f;
  const float y = fmaf(ry, 128.f, oy) - 0.5f;
  const float xf = floorf(x), yf = floorf(y);
  const float wx = x - xf, wy = y - yf;
  const int ix = (int)xf, iy = (int)yf;
  float xw0 = 1.f - wx, xw1 = wx, yw0 = 1.f - wy, yw1 = wy;
  if (ix < 0 || ix > 127)   xw0 = 0.f;
  if (ix < -1 || ix > 126)  xw1 = 0.f;
  if (iy < 0 || iy > 127)   yw0 = 0.f;
  if (iy < -1 || iy > 126)  yw1 = 0.f;
  const int ix0 = min(max(ix, 0), 127), ix1 = min(max(ix + 1, 0), 127);
  const int iy0 = min(max(iy, 0), 127), iy1 = min(max(iy + 1, 0), 127);
  const float t0 = awp * yw0, t1 = awp * yw1;
  pk01 = pk2h(t0 * xw0, t0 * xw1);     // (row0: x0-w, x1-w) fp16
  pk23 = pk2h(t1 * xw0, t1 * xw1);     // (row1: x0-w, x1-w) fp16
  word = (u32)(iy0 * 128 + ix0) | ((u32)(ix1 - ix0) << 16) | ((u32)(iy1 - iy0) << 17);
}

__global__ __launch_bounds__(256) void k_sampler(const float* __restrict__ rp,
    const float* __restrict__ offw, const float* __restrict__ logit,
    const char* __restrict__ vfp8, short* __restrict__ O2b){
  const int tid = threadIdx.x;
  const int j3 = tid & 7;               // lane in group
  const int cj = j3 & 3;                // hd chunk (8 channels = 8 B fp8)
  const int px = j3 >> 2;               // pixel side (x0 / x1)
  const int grp = tid >> 3;             // query in block: 0..31
  const int lane = tid & 63;
  const int glane8 = lane & ~7;
  const int h = blockIdx.x & 7;
  const int q = (blockIdx.x >> 3) * 32 + grp;
  const u32 cjof = (u32)cj * 8;         // byte offset of my channel chunk
  const u32 selw = px ? 0x03020706u : 0x01000504u;

  // per-lane softmax weight for p = j3 (8-lane shfl_xor reduce)
  const float* lp = logit + (size_t)q * 64 + h * 8;
  const float l = lp[j3];
  float m = l;
  m = fmaxf(m, __shfl_xor(m, 1)); m = fmaxf(m, __shfl_xor(m, 2)); m = fmaxf(m, __shfl_xor(m, 4));
  const float e = __expf(l - m);
  float ssum = e;
  ssum += __shfl_xor(ssum, 1); ssum += __shfl_xor(ssum, 2); ssum += __shfl_xor(ssum, 4);
  const float awp = e * (0.5f / ssum);

  const float* offp = offw + (size_t)q * 128 + h * 16;
  const float ox = offp[2 * j3], oy = offp[2 * j3 + 1];
  const int za2 = (j3 & 3) * 2;
  const float rx0 = rp[(size_t)q * 8 + za2],        ry0 = rp[(size_t)q * 8 + za2 + 1];
  const float rx1 = rp[(size_t)(QN + q) * 8 + za2], ry1 = rp[(size_t)(QN + q) * 8 + za2 + 1];

  u32 wrdA, pkA01, pkA23, wrdB, pkB01, pkB23;
  mkw(rx0, ry0, ox, oy, awp, wrdA, pkA01, pkA23);   // r=0 sample
  mkw(rx1, ry1, ox, oy, awp, wrdB, pkB01, pkB23);   // r=1 sample

  const char* vb0 = vfp8 + (size_t)(h * QN) * 32;
  const char* vb1 = vfp8 + (size_t)((8 + h) * QN) * 32;

  float acc[8] = {0.f,0.f,0.f,0.f,0.f,0.f,0.f,0.f};

#define LOADP(S, WRD, VB)                                                   \
  const u32 wd_##S = __shfl((WRD), glane8 | ((S) & 7));                     \
  const u32 o0_##S = (wd_##S & 0xFFFFu) * 32u + cjof                        \
                   + (px ? ((wd_##S >> 11) & 32u) : 0u);                    \
  const u32 o1_##S = o0_##S + ((wd_##S >> 17) & 1u) * 4096u;                \
  const u32x2 cA_##S = *(const u32x2*)((VB) + o0_##S);  /* row y0, 8 ch */  \
  const u32x2 cB_##S = *(const u32x2*)((VB) + o1_##S);  /* row y1, 8 ch */

#define USEP(S, PK01, PK23) do{                                             \
    const int srcl_ = glane8 | ((S) & 7);                                   \
    const u32 w01_ = __shfl((PK01), srcl_);                                 \
    const u32 w23_ = __shfl((PK23), srcl_);                                 \
    const h2_t wp_ = __builtin_bit_cast(h2_t, bperm(w01_, w23_, selw));     \
    const float w0_ = (float)wp_[0], w1_ = (float)wp_[1];                   \
    _Pragma("unroll")                                                       \
    for (int wdi_ = 0; wdi_ < 2; ++wdi_){                                   \
      const f2_t aL_ = upk_fp8<false>(cA_##S[wdi_]);                        \
      const f2_t aH_ = upk_fp8<true >(cA_##S[wdi_]);                        \
      const f2_t bL_ = upk_fp8<false>(cB_##S[wdi_]);                        \
      const f2_t bH_ = upk_fp8<true >(cB_##S[wdi_]);                        \
      acc[4*wdi_+0] = fmaf(w0_, aL_[0], fmaf(w1_, bL_[0], acc[4*wdi_+0]));  \
      acc[4*wdi_+1] = fmaf(w0_, aL_[1], fmaf(w1_, bL_[1], acc[4*wdi_+1]));  \
      acc[4*wdi_+2] = fmaf(w0_, aH_[0], fmaf(w1_, bH_[0], acc[4*wdi_+2]));  \
      acc[4*wdi_+3] = fmaf(w0_, aH_[1], fmaf(w1_, bH_[1], acc[4*wdi_+3]));  \
    }                                                                       \
  }while(0)

  LOADP(0,  wrdA, vb0) LOADP(1,  wrdA, vb0) LOADP(2,  wrdA, vb0)
  USEP(0,  pkA01, pkA23); LOADP(3,  wrdA, vb0)
  USEP(1,  pkA01, pkA23); LOADP(4,  wrdA, vb0)
  USEP(2,  pkA01, pkA23); LOADP(5,  wrdA, vb0)
  USEP(3,  pkA01, pkA23); LOADP(6,  wrdA, vb0)
  USEP(4,  pkA01, pkA23); LOADP(7,  wrdA, vb0)
  USEP(5,  pkA01, pkA23); LOADP(8,  wrdB, vb1)
  USEP(6,  pkA01, pkA23); LOADP(9,  wrdB, vb1)
  USEP(7,  pkA01, pkA23); LOADP(10, wrdB, vb1)
  USEP(8,  pkB01, pkB23); LOADP(11, wrdB, vb1)
  USEP(9,  pkB01, pkB23); LOADP(12, wrdB, vb1)
  USEP(10, pkB01, pkB23); LOADP(13, wrdB, vb1)
  USEP(11, pkB01, pkB23); LOADP(14, wrdB, vb1)
  USEP(12, pkB01, pkB23); LOADP(15, wrdB, vb1)
  USEP(13, pkB01, pkB23);
  USEP(14, pkB01, pkB23);
  USEP(15, pkB01, pkB23);
#undef LOADP
#undef USEP

  // combine pixel-side partials (px=0 + px=1), write bf16 O2
  #pragma unroll
  for (int i = 0; i < 8; ++i) acc[i] += __shfl_xor(acc[i], 4);
  if (px == 0){
    s16x8 o = { f2bf(acc[0]), f2bf(acc[1]), f2bf(acc[2]), f2bf(acc[3]),
                f2bf(acc[4]), f2bf(acc[5]), f2bf(acc[6]), f2bf(acc[7]) };
    *(s16x8*)(O2b + (size_t)q * DK + h * 32 + cj * 8) = o;
  }
}

extern "C" void kernel_launch(void* const* d_in, const int* in_sizes, int n_in,
                              void* d_out, int out_size, void* d_ws, size_t ws_size,
                              hipStream_t stream) {
  const float* query = (const float*)d_in[0];
  const float* value = (const float*)d_in[1];
  const float* refpt = (const float*)d_in[2];
  // d_in[3] spatial_shapes: fixed [[128,128]], hardcoded
  const float* W_off  = (const float*)d_in[4];
  const float* b_off  = (const float*)d_in[5];
  const float* W_attn = (const float*)d_in[6];
  const float* b_attn = (const float*)d_in[7];
  const float* W_val  = (const float*)d_in[8];
  const float* b_val  = (const float*)d_in[9];
  const float* W_out  = (const float*)d_in[10];
  const float* b_out  = (const float*)d_in[11];
  float* out = (float*)d_out;

  char* ws = (char*)d_ws;
  char*  vfp8 = (char*)(ws);                     // 2*8*16384*32 fp8      (8388608 B)
  float* offw = (float*)(ws + 8388608);          // 16384*128 f32         (8388608 B)
  float* logit= (float*)(ws + 16777216);         // 16384*64 f32          (4194304 B)
  short* O2b  = (short*)(ws + 20971520);         // 16384*256 bf16        (8388608 B)

  k_proj    <<<dim3(1024), dim3(256), 0, stream>>>(value, query, W_val, W_off, W_attn,
                                                   b_val, b_off, b_attn, vfp8, offw, logit);
  k_sampler <<<dim3(4096), dim3(256), 0, stream>>>(refpt, offw, logit, vfp8, O2b);
  k_gemm_out<<<dim3(512),  dim3(256), 0, stream>>>(O2b, W_out, b_out, query, out);
}

// Round 13
// 67.600 us; speedup vs baseline: 1.0038x; 1.0038x over previous
//
#include <hip/hip_runtime.h>
#include <hip/hip_bf16.h>
#include <hip/hip_fp16.h>
#include <hip/hip_fp8.h>

// Problem constants: B=1,R=2,D=256,NH=8,NP=8,ZA=4,H=W=128,Q=16384,HD=32
#define QN 16384
#define DK 256

typedef float f4_t __attribute__((ext_vector_type(4)));
typedef float f2_t __attribute__((ext_vector_type(2)));
typedef short s16x8 __attribute__((ext_vector_type(8)));
typedef short s16x4 __attribute__((ext_vector_type(4)));
typedef unsigned int u32;
typedef u32 u32x4 __attribute__((ext_vector_type(4)));
typedef u32 u32x2 __attribute__((ext_vector_type(2)));
typedef __fp16 h2_t __attribute__((ext_vector_type(2)));

__device__ inline short f2bf(float f){
  __hip_bfloat16 h = __float2bfloat16(f);
  return __builtin_bit_cast(short, h);
}
__device__ inline u32 pk2h(float a, float b){
#if __has_builtin(__builtin_amdgcn_cvt_pkrtz)
  h2_t r = __builtin_amdgcn_cvt_pkrtz(a, b);
  return __builtin_bit_cast(u32, r);
#else
  return (u32)__builtin_bit_cast(unsigned short, __float2half(a)) |
         ((u32)__builtin_bit_cast(unsigned short, __float2half(b)) << 16);
#endif
}
// fp8 e4m3 pack (2 floats -> low 16 bits) / unpack (HI = immediate template arg)
__device__ inline u32 pk_fp8(float a, float b){
#if __has_builtin(__builtin_amdgcn_cvt_pk_fp8_f32)
  return (u32)__builtin_amdgcn_cvt_pk_fp8_f32(a, b, 0, false);
#else
  __hip_fp8_e4m3 fa(a), fb(b);
  return (u32)fa.__x | ((u32)fb.__x << 8);
#endif
}
template<bool HI>
__device__ inline f2_t upk_fp8(u32 w){
#if __has_builtin(__builtin_amdgcn_cvt_pk_f32_fp8)
  return __builtin_amdgcn_cvt_pk_f32_fp8(w, HI);
#else
  const u32 hh = HI ? (w >> 16) : (w & 0xFFFFu);
  __hip_fp8_e4m3 a, b;
  a.__x = (unsigned char)(hh & 0xFF);
  b.__x = (unsigned char)(hh >> 8);
  return (f2_t){(float)a, (float)b};
#endif
}
// load 8 f32 weights and pack to bf16x8
__device__ inline s16x8 ldw8(const float* __restrict__ src){
  const f4_t v0 = *(const f4_t*)src;
  const f4_t v1 = *(const f4_t*)(src + 4);
  s16x8 o = { f2bf(v0[0]), f2bf(v0[1]), f2bf(v0[2]), f2bf(v0[3]),
              f2bf(v1[0]), f2bf(v1[1]), f2bf(v1[2]), f2bf(v1[3]) };
  return o;
}

// =============== K1: fused projection GEMM ======================================
// bid < 512:  value-proj tile (BM=64) -> fp8 gather layout vfp8 (LDS-transposed)
// bid >= 512: offset/logit tile (BM=32) -> offw/logit f32
__global__ __launch_bounds__(256, 2) void k_proj(const float* __restrict__ value,
    const float* __restrict__ query, const float* __restrict__ Wval,
    const float* __restrict__ Woff, const float* __restrict__ Wattn,
    const float* __restrict__ bval, const float* __restrict__ boff,
    const float* __restrict__ battn, char* __restrict__ vfp8,
    float* __restrict__ offw, float* __restrict__ logit){
  __shared__ short As[64 * 256];
  __shared__ short Bs[64 * 256];
  __shared__ u32 Cs[64 * 16];                 // 4KB fp8 transpose buffer (val path)
  const int tid = threadIdx.x;
  const int lane = tid & 63, wv = tid >> 6;
  const int r16 = lane & 15, kh = lane >> 4;
  const int swsel = (r16 & 7) << 4;
  const int bid = blockIdx.x;

  if (bid < 512){
    // ---------------- value-projection path (BM=64) ----------------
    const float* A = value;
    const int mbase = bid * 64;
    #pragma unroll
    for (int i = 0; i < 16; ++i){
      const int lin = i * 256 + tid;
      const int r = lin >> 6, ck = lin & 63;
      const f4_t v = *(const f4_t*)(A + (size_t)(mbase + r) * DK + ck * 4);
      s16x4 o = { f2bf(v[0]), f2bf(v[1]), f2bf(v[2]), f2bf(v[3]) };
      *(s16x4*)((char*)As + r * 512 + ((ck * 8) ^ ((r & 7) << 4))) = o;
    }
    s16x8 breg[8];
    #pragma unroll
    for (int i = 0; i < 8; ++i){
      const int lin = i * 256 + tid;
      const int n = lin >> 5, ck = lin & 31;
      breg[i] = ldw8(Wval + (size_t)n * DK + ck * 8);
    }
    __syncthreads();
    for (int cg = 0; cg < 4; ++cg){
      #pragma unroll
      for (int i = 0; i < 8; ++i){
        const int lin = i * 256 + tid;
        const int n = lin >> 5, ck = lin & 31;
        *(s16x8*)((char*)Bs + n * 512 + ((ck * 16) ^ ((n & 7) << 4))) = breg[i];
      }
      __syncthreads();
      if (cg < 3){
        #pragma unroll
        for (int i = 0; i < 8; ++i){
          const int lin = i * 256 + tid;
          const int n = lin >> 5, ck = lin & 31;
          breg[i] = ldw8(Wval + (size_t)((cg + 1) * 64 + n) * DK + ck * 8);
        }
      }
      f4_t acc[4];
      #pragma unroll
      for (int i = 0; i < 4; ++i) acc[i] = (f4_t){0.f, 0.f, 0.f, 0.f};
      #pragma unroll
      for (int kk = 0; kk < 8; ++kk){
        const int kb = kh * 16 + kk * 64;
        const s16x8 a = *(const s16x8*)((char*)As + (wv * 16 + r16) * 512 + (kb ^ swsel));
        #pragma unroll
        for (int nt = 0; nt < 4; ++nt){
          const s16x8 b = *(const s16x8*)((char*)Bs + (nt * 16 + r16) * 512 + (kb ^ swsel));
          acc[nt] = __builtin_amdgcn_mfma_f32_16x16x32_bf16(a, b, acc[nt], 0, 0, 0);
        }
      }
      // epilogue: f32 -> fp8, LDS transpose, coalesced 16B stores
      #pragma unroll
      for (int nt = 0; nt < 4; ++nt){
        const int n = cg * 64 + nt * 16 + r16;
        const float bv = bval[n];
        #pragma unroll
        for (int rix = 0; rix < 4; ++rix){
          const float vv = acc[nt][rix] + bv;
          ((char*)Cs)[(wv * 16 + kh * 4 + rix) * 64 + nt * 16 + r16] =
              (char)(pk_fp8(vv, 0.f) & 0xFFu);
        }
      }
      __syncthreads();                          // Cs ready; also fences Bs reads
      {
        const u32x4 cw = *((const u32x4*)((const char*)Cs + tid * 16));
        const int pixl = tid >> 2, q4 = tid & 3;
        const int h2 = cg * 2 + (q4 >> 1);
        const int m = mbase + pixl;
        const int r = m >> 14, pix = m & (QN - 1);
        *(u32x4*)(vfp8 + ((size_t)((r * 8 + h2) * QN + pix)) * 32 + (q4 & 1) * 16) = cw;
      }
    }
  } else {
    // ---------------- offset/logit path (BM=32) ----------------
    const float* A = query;
    const int mg = wv & 1, ch = wv >> 1;
    const int mbase = (bid - 512) * 32;
    #pragma unroll
    for (int i = 0; i < 8; ++i){
      const int lin = i * 256 + tid;
      const int r = lin >> 6, ck = lin & 63;
      const f4_t v = *(const f4_t*)(A + (size_t)(mbase + r) * DK + ck * 4);
      s16x4 o = { f2bf(v[0]), f2bf(v[1]), f2bf(v[2]), f2bf(v[3]) };
      *(s16x4*)((char*)As + r * 512 + ((ck * 8) ^ ((r & 7) << 4))) = o;
    }
    s16x8 breg[8];
    #pragma unroll
    for (int i = 0; i < 8; ++i){
      const int lin = i * 256 + tid;
      const int n = lin >> 5, ck = lin & 31;
      breg[i] = ldw8(Woff + (size_t)n * DK + ck * 8);
    }
    __syncthreads();
    for (int cg = 0; cg < 3; ++cg){
      #pragma unroll
      for (int i = 0; i < 8; ++i){
        const int lin = i * 256 + tid;
        const int n = lin >> 5, ck = lin & 31;
        *(s16x8*)((char*)Bs + n * 512 + ((ck * 16) ^ ((n & 7) << 4))) = breg[i];
      }
      __syncthreads();
      if (cg < 2){
        #pragma unroll
        for (int i = 0; i < 8; ++i){
          const int lin = i * 256 + tid;
          const int n = lin >> 5, ck = lin & 31;
          const int rrow = (cg + 1) * 64 + n;     // [64,192)
          const float* src = (rrow < 128) ? (Woff  + (size_t)rrow * DK)
                                          : (Wattn + (size_t)(rrow - 128) * DK);
          breg[i] = ldw8(src + ck * 8);
        }
      }
      f4_t acc[2];
      acc[0] = (f4_t){0.f,0.f,0.f,0.f}; acc[1] = (f4_t){0.f,0.f,0.f,0.f};
      #pragma unroll
      for (int kk = 0; kk < 8; ++kk){
        const int kb = kh * 16 + kk * 64;
        const s16x8 a = *(const s16x8*)((char*)As + (mg * 16 + r16) * 512 + (kb ^ swsel));
        #pragma unroll
        for (int nt = 0; nt < 2; ++nt){
          const s16x8 b = *(const s16x8*)((char*)Bs + (ch * 32 + nt * 16 + r16) * 512 + (kb ^ swsel));
          acc[nt] = __builtin_amdgcn_mfma_f32_16x16x32_bf16(a, b, acc[nt], 0, 0, 0);
        }
      }
      #pragma unroll
      for (int nt = 0; nt < 2; ++nt){
        const int n = cg * 64 + ch * 32 + nt * 16 + r16;
        #pragma unroll
        for (int rix = 0; rix < 4; ++rix){
          const int m = mbase + mg * 16 + kh * 4 + rix;
          const float v = acc[nt][rix];
          if (n < 128) offw[(size_t)m * 128 + n] = v + boff[n];
          else         logit[(size_t)m * 64 + (n - 128)] = v + battn[n - 128];
        }
      }
      __syncthreads();
    }
  }
}

// =============== K4: output projection + bias + residual, BM=32 =================
__global__ __launch_bounds__(256, 2) void k_gemm_out(const short* __restrict__ Ab,
    const float* __restrict__ Wout, const float* __restrict__ bout,
    const float* __restrict__ query, float* __restrict__ out){
  __shared__ short As[32 * 256];
  __shared__ short Bs[64 * 256];
  const int tid = threadIdx.x;
  const int lane = tid & 63, wv = tid >> 6;
  const int r16 = lane & 15, kh = lane >> 4;
  const int mg = wv & 1, ch = wv >> 1;
  const int swsel = (r16 & 7) << 4;
  const int mbase = blockIdx.x * 32;

  #pragma unroll
  for (int i = 0; i < 4; ++i){
    const int lin = i * 256 + tid;
    const int r = lin >> 5, ck = lin & 31;
    const s16x8 v = *(const s16x8*)(Ab + (size_t)(mbase + r) * DK + ck * 8);
    *(s16x8*)((char*)As + r * 512 + ((ck * 16) ^ ((r & 7) << 4))) = v;
  }
  s16x8 breg[8];
  #pragma unroll
  for (int i = 0; i < 8; ++i){
    const int lin = i * 256 + tid;
    const int n = lin >> 5, ck = lin & 31;
    breg[i] = ldw8(Wout + (size_t)n * DK + ck * 8);
  }
  __syncthreads();

  for (int cg = 0; cg < 4; ++cg){
    #pragma unroll
    for (int i = 0; i < 8; ++i){
      const int lin = i * 256 + tid;
      const int n = lin >> 5, ck = lin & 31;
      *(s16x8*)((char*)Bs + n * 512 + ((ck * 16) ^ ((n & 7) << 4))) = breg[i];
    }
    __syncthreads();
    if (cg < 3){
      #pragma unroll
      for (int i = 0; i < 8; ++i){
        const int lin = i * 256 + tid;
        const int n = lin >> 5, ck = lin & 31;
        breg[i] = ldw8(Wout + (size_t)((cg + 1) * 64 + n) * DK + ck * 8);
      }
    }
    f4_t acc[2];
    acc[0] = (f4_t){0.f,0.f,0.f,0.f}; acc[1] = (f4_t){0.f,0.f,0.f,0.f};
    #pragma unroll
    for (int kk = 0; kk < 8; ++kk){
      const int kb = kh * 16 + kk * 64;
      const s16x8 a = *(const s16x8*)((char*)As + (mg * 16 + r16) * 512 + (kb ^ swsel));
      #pragma unroll
      for (int nt = 0; nt < 2; ++nt){
        const s16x8 b = *(const s16x8*)((char*)Bs + (ch * 32 + nt * 16 + r16) * 512 + (kb ^ swsel));
        acc[nt] = __builtin_amdgcn_mfma_f32_16x16x32_bf16(a, b, acc[nt], 0, 0, 0);
      }
    }
    #pragma unroll
    for (int nt = 0; nt < 2; ++nt){
      const int n = cg * 64 + ch * 32 + nt * 16 + r16;
      const float bo = bout[n];
      #pragma unroll
      for (int rix = 0; rix < 4; ++rix){
        const int m = mbase + mg * 16 + kh * 4 + rix;
        out[(size_t)m * DK + n] = acc[nt][rix] + bo + query[(size_t)m * DK + n];
      }
    }
    __syncthreads();
  }
}

// ---------------- K3: bilinear sampling, fp8 v-cache, 16B-per-lane loads --------
// 8-lane group per (q,h). Lane j3 = (row2 = j3>>2, px2 = (j3>>1)&1, ck2 = j3&1):
// ONE dwordx4 load per sample (16 channels of corner pixel (x_px2, y_row2)) —
// halves gather-instruction count vs the 2x8B scheme. Weight = fp16 (row2,px2)
// slice of the broadcast words. Final reduce: shfl_xor(4) rows + shfl_xor(2) px.
__device__ inline void mkw(float rx, float ry, float ox, float oy, float awp,
                           u32& word, u32& pk01, u32& pk23){
  const float x = fmaf(rx, 128.f, ox) - 0.5f;
  const float y = fmaf(ry, 128.f, oy) - 0.5f;
  const float xf = floorf(x), yf = floorf(y);
  const float wx = x - xf, wy = y - yf;
  const int ix = (int)xf, iy = (int)yf;
  float xw0 = 1.f - wx, xw1 = wx, yw0 = 1.f - wy, yw1 = wy;
  if (ix < 0 || ix > 127)   xw0 = 0.f;
  if (ix < -1 || ix > 126)  xw1 = 0.f;
  if (iy < 0 || iy > 127)   yw0 = 0.f;
  if (iy < -1 || iy > 126)  yw1 = 0.f;
  const int ix0 = min(max(ix, 0), 127), ix1 = min(max(ix + 1, 0), 127);
  const int iy0 = min(max(iy, 0), 127), iy1 = min(max(iy + 1, 0), 127);
  const float t0 = awp * yw0, t1 = awp * yw1;
  pk01 = pk2h(t0 * xw0, t0 * xw1);     // (row0: x0-w, x1-w) fp16
  pk23 = pk2h(t1 * xw0, t1 * xw1);     // (row1: x0-w, x1-w) fp16
  word = (u32)(iy0 * 128 + ix0) | ((u32)(ix1 - ix0) << 16) | ((u32)(iy1 - iy0) << 17);
}

__global__ __launch_bounds__(256) void k_sampler(const float* __restrict__ rp,
    const float* __restrict__ offw, const float* __restrict__ logit,
    const char* __restrict__ vfp8, short* __restrict__ O2b){
  const int tid = threadIdx.x;
  const int j3 = tid & 7;               // lane in group
  const int row2 = j3 >> 2;             // row (y0 / y1)
  const int px2 = (j3 >> 1) & 1;        // pixel side (x0 / x1)
  const int ck2 = j3 & 1;               // channel half: [16*ck2, 16*ck2+16)
  const int grp = tid >> 3;             // query in block: 0..31
  const int lane = tid & 63;
  const int glane8 = lane & ~7;
  const int h = blockIdx.x & 7;
  const int q = (blockIdx.x >> 3) * 32 + grp;
  const u32 laneof = (u32)ck2 * 16;     // byte offset of my channel half

  // per-lane softmax weight for p = j3 (8-lane shfl_xor reduce)
  const float* lp = logit + (size_t)q * 64 + h * 8;
  const float l = lp[j3];
  float m = l;
  m = fmaxf(m, __shfl_xor(m, 1)); m = fmaxf(m, __shfl_xor(m, 2)); m = fmaxf(m, __shfl_xor(m, 4));
  const float e = __expf(l - m);
  float ssum = e;
  ssum += __shfl_xor(ssum, 1); ssum += __shfl_xor(ssum, 2); ssum += __shfl_xor(ssum, 4);
  const float awp = e * (0.5f / ssum);

  const float* offp = offw + (size_t)q * 128 + h * 16;
  const float ox = offp[2 * j3], oy = offp[2 * j3 + 1];
  const int za2 = (j3 & 3) * 2;
  const float rx0 = rp[(size_t)q * 8 + za2],        ry0 = rp[(size_t)q * 8 + za2 + 1];
  const float rx1 = rp[(size_t)(QN + q) * 8 + za2], ry1 = rp[(size_t)(QN + q) * 8 + za2 + 1];

  u32 wrdA, pkA01, pkA23, wrdB, pkB01, pkB23;
  mkw(rx0, ry0, ox, oy, awp, wrdA, pkA01, pkA23);   // r=0 sample (owner: lane j3 = p)
  mkw(rx1, ry1, ox, oy, awp, wrdB, pkB01, pkB23);   // r=1 sample

  const char* vb0 = vfp8 + (size_t)(h * QN) * 32;
  const char* vb1 = vfp8 + (size_t)((8 + h) * QN) * 32;

  float acc[16];
  #pragma unroll
  for (int i = 0; i < 16; ++i) acc[i] = 0.f;

  // LOADP: one 16B gather for my (row2, px2, ck2) slice of sample S.
#define LOADP(S, WRD, VB)                                                   \
  const u32 wd_##S = __shfl((WRD), glane8 | ((S) & 7));                     \
  const u32 ad_##S = (wd_##S & 0xFFFFu) * 32u + laneof                      \
                   + (px2 ? ((wd_##S >> 11) & 32u) : 0u)                    \
                   + (row2 ? ((wd_##S >> 17) & 1u) * 4096u : 0u);           \
  const u32x4 c_##S = *(const u32x4*)((VB) + ad_##S);

#define USEP(S, PK01, PK23) do{                                             \
    const int srcl_ = glane8 | ((S) & 7);                                   \
    const u32 w01_ = __shfl((PK01), srcl_);                                 \
    const u32 w23_ = __shfl((PK23), srcl_);                                 \
    const u32 wsel_ = row2 ? w23_ : w01_;                                   \
    const h2_t wh_ = __builtin_bit_cast(h2_t, wsel_);                       \
    const float w_ = px2 ? (float)wh_[1] : (float)wh_[0];                   \
    _Pragma("unroll")                                                       \
    for (int i_ = 0; i_ < 4; ++i_){                                         \
      const f2_t lo_ = upk_fp8<false>(c_##S[i_]);                           \
      const f2_t hi_ = upk_fp8<true >(c_##S[i_]);                           \
      acc[4*i_+0] = fmaf(w_, lo_[0], acc[4*i_+0]);                          \
      acc[4*i_+1] = fmaf(w_, lo_[1], acc[4*i_+1]);                          \
      acc[4*i_+2] = fmaf(w_, hi_[0], acc[4*i_+2]);                          \
      acc[4*i_+3] = fmaf(w_, hi_[1], acc[4*i_+3]);                          \
    }                                                                       \
  }while(0)

  LOADP(0,  wrdA, vb0) LOADP(1,  wrdA, vb0) LOADP(2,  wrdA, vb0)
  USEP(0,  pkA01, pkA23); LOADP(3,  wrdA, vb0)
  USEP(1,  pkA01, pkA23); LOADP(4,  wrdA, vb0)
  USEP(2,  pkA01, pkA23); LOADP(5,  wrdA, vb0)
  USEP(3,  pkA01, pkA23); LOADP(6,  wrdA, vb0)
  USEP(4,  pkA01, pkA23); LOADP(7,  wrdA, vb0)
  USEP(5,  pkA01, pkA23); LOADP(8,  wrdB, vb1)
  USEP(6,  pkA01, pkA23); LOADP(9,  wrdB, vb1)
  USEP(7,  pkA01, pkA23); LOADP(10, wrdB, vb1)
  USEP(8,  pkB01, pkB23); LOADP(11, wrdB, vb1)
  USEP(9,  pkB01, pkB23); LOADP(12, wrdB, vb1)
  USEP(10, pkB01, pkB23); LOADP(13, wrdB, vb1)
  USEP(11, pkB01, pkB23); LOADP(14, wrdB, vb1)
  USEP(12, pkB01, pkB23); LOADP(15, wrdB, vb1)
  USEP(13, pkB01, pkB23);
  USEP(14, pkB01, pkB23);
  USEP(15, pkB01, pkB23);
#undef LOADP
#undef USEP

  // reduce: rows (xor 4) then pixel sides (xor 2); lanes 0,1 hold final 16 ch each
  #pragma unroll
  for (int i = 0; i < 16; ++i) acc[i] += __shfl_xor(acc[i], 4);
  #pragma unroll
  for (int i = 0; i < 16; ++i) acc[i] += __shfl_xor(acc[i], 2);
  if (j3 < 2){
    short* op = O2b + (size_t)q * DK + h * 32 + j3 * 16;
    s16x8 o0 = { f2bf(acc[0]),  f2bf(acc[1]),  f2bf(acc[2]),  f2bf(acc[3]),
                 f2bf(acc[4]),  f2bf(acc[5]),  f2bf(acc[6]),  f2bf(acc[7]) };
    s16x8 o1 = { f2bf(acc[8]),  f2bf(acc[9]),  f2bf(acc[10]), f2bf(acc[11]),
                 f2bf(acc[12]), f2bf(acc[13]), f2bf(acc[14]), f2bf(acc[15]) };
    *(s16x8*)op       = o0;
    *(s16x8*)(op + 8) = o1;
  }
}

extern "C" void kernel_launch(void* const* d_in, const int* in_sizes, int n_in,
                              void* d_out, int out_size, void* d_ws, size_t ws_size,
                              hipStream_t stream) {
  const float* query = (const float*)d_in[0];
  const float* value = (const float*)d_in[1];
  const float* refpt = (const float*)d_in[2];
  // d_in[3] spatial_shapes: fixed [[128,128]], hardcoded
  const float* W_off  = (const float*)d_in[4];
  const float* b_off  = (const float*)d_in[5];
  const float* W_attn = (const float*)d_in[6];
  const float* b_attn = (const float*)d_in[7];
  const float* W_val  = (const float*)d_in[8];
  const float* b_val  = (const float*)d_in[9];
  const float* W_out  = (const float*)d_in[10];
  const float* b_out  = (const float*)d_in[11];
  float* out = (float*)d_out;

  char* ws = (char*)d_ws;
  char*  vfp8 = (char*)(ws);                     // 2*8*16384*32 fp8      (8388608 B)
  float* offw = (float*)(ws + 8388608);          // 16384*128 f32         (8388608 B)
  float* logit= (float*)(ws + 16777216);         // 16384*64 f32          (4194304 B)
  short* O2b  = (short*)(ws + 20971520);         // 16384*256 bf16        (8388608 B)

  k_proj    <<<dim3(1024), dim3(256), 0, stream>>>(value, query, W_val, W_off, W_attn,
                                                   b_val, b_off, b_attn, vfp8, offw, logit);
  k_sampler <<<dim3(4096), dim3(256), 0, stream>>>(refpt, offw, logit, vfp8, O2b);
  k_gemm_out<<<dim3(512),  dim3(256), 0, stream>>>(O2b, W_out, b_out, query, out);
}